// Round 1
// baseline (2167.176 us; speedup 1.0000x reference)
//
#include <hip/hip_runtime.h>
#include <math.h>

#define Z 512
#define XV 10000
#define SEQ 256
#define NB 64

__device__ __forceinline__ void online_combine(float& m, float& s, float pm, float ps) {
    if (pm > m) { s = s * __expf(m - pm) + ps; m = pm; }
    else        { s = s + ps * __expf(pm - m); }
}

// K1: column-wise LSE of T over axis 0 (rows). grid=8 (64 cols each), block=256.
__global__ void k_t_collse(const float* __restrict__ T, float* __restrict__ colLSE) {
    __shared__ float ms[256], ss[256];
    const int tid = threadIdx.x;
    const int c0 = blockIdx.x * 64;
    const int cl = tid & 63;
    const int r0 = tid >> 6;           // 0..3
    const int c  = c0 + cl;
    float m = -INFINITY, s = 0.f;
    for (int r = r0; r < Z; r += 4)
        online_combine(m, s, T[(size_t)r * Z + c], 1.f);
    ms[tid] = m; ss[tid] = s;
    __syncthreads();
    if (tid < 128) {
        m = ms[tid]; s = ss[tid];
        online_combine(m, s, ms[tid + 128], ss[tid + 128]);
        ms[tid] = m; ss[tid] = s;
    }
    __syncthreads();
    if (tid < 64) {
        m = ms[tid]; s = ss[tid];
        online_combine(m, s, ms[tid + 64], ss[tid + 64]);
        colLSE[c0 + tid] = m + __logf(s);
    }
}

// K2: emit column-wise LSE partials. grid=256 (8 colgroups x 32 rowgroups), block=256.
__global__ void k_emit_part(const float* __restrict__ emit, float2* __restrict__ part) {
    __shared__ float ms[256], ss[256];
    const int tid = threadIdx.x;
    const int g  = blockIdx.x & 7;
    const int rg = blockIdx.x >> 3;
    const int cl = tid & 63;
    const int r0 = tid >> 6;
    const int c  = g * 64 + cl;
    const int rstart = rg * 313;
    const int rend   = (rstart + 313 < XV) ? rstart + 313 : XV;
    float m = -INFINITY, s = 0.f;
    for (int r = rstart + r0; r < rend; r += 4)
        online_combine(m, s, emit[(size_t)r * Z + c], 1.f);
    ms[tid] = m; ss[tid] = s;
    __syncthreads();
    if (tid < 128) {
        m = ms[tid]; s = ss[tid];
        online_combine(m, s, ms[tid + 128], ss[tid + 128]);
        ms[tid] = m; ss[tid] = s;
    }
    __syncthreads();
    if (tid < 64) {
        m = ms[tid]; s = ss[tid];
        online_combine(m, s, ms[tid + 64], ss[tid + 64]);
        part[(size_t)rg * Z + g * 64 + tid] = make_float2(m, s);
    }
}

// K3: finalize emit_lse per state; compute pi_eff = pi_log - emit_lse. grid=1, block=512.
__global__ void k_finalize(const float2* __restrict__ part, const float* __restrict__ pi,
                           float* __restrict__ emit_lse, float* __restrict__ pi_eff) {
    __shared__ float sm[512];
    const int z = threadIdx.x;
    float m = -INFINITY, s = 0.f;
    for (int rg = 0; rg < 32; ++rg) {
        float2 p = part[(size_t)rg * Z + z];
        online_combine(m, s, p.x, p.y);
    }
    const float el = m + __logf(s);
    emit_lse[z] = el;
    // LSE of pi across the block
    const float v = pi[z];
    sm[z] = v; __syncthreads();
    for (int off = 256; off > 0; off >>= 1) {
        if (z < off) sm[z] = fmaxf(sm[z], sm[z + off]);
        __syncthreads();
    }
    const float mx = sm[0];
    __syncthreads();
    sm[z] = __expf(v - mx); __syncthreads();
    for (int off = 256; off > 0; off >>= 1) {
        if (z < off) sm[z] += sm[z + off];
        __syncthreads();
    }
    const float lse_pi = mx + __logf(sm[0]);
    pi_eff[z] = (v - lse_pi) - el;
}

// K4: build E_Tt[i*Z + j] = exp(T_log[j,i] - m_T[j]); adj[j] = m_T[j] - emit_lse[j].
// grid=512 (one block per row j), block=256.
__global__ void k_build_ET(const float* __restrict__ T, const float* __restrict__ colLSE,
                           const float* __restrict__ emit_lse,
                           float* __restrict__ E_Tt, float* __restrict__ adj) {
    __shared__ float sm[256];
    const int j = blockIdx.x, t = threadIdx.x;
    const float v0 = T[(size_t)j * Z + t]       - colLSE[t];
    const float v1 = T[(size_t)j * Z + t + 256] - colLSE[t + 256];
    float m = fmaxf(v0, v1);
    sm[t] = m; __syncthreads();
    for (int off = 128; off > 0; off >>= 1) {
        if (t < off) sm[t] = fmaxf(sm[t], sm[t + off]);
        __syncthreads();
    }
    const float mT = sm[0];
    E_Tt[(size_t)t * Z + j]         = __expf(v0 - mT);
    E_Tt[(size_t)(t + 256) * Z + j] = __expf(v1 - mT);
    if (t == 0) adj[j] = mT - emit_lse[j];
}

// K5: the sequential scan. One block per batch element; thread j owns state j.
__global__ void __launch_bounds__(512, 1)
k_hmm_scan(const int* __restrict__ ids, const float* __restrict__ emit,
           const float* __restrict__ E_Tt, const float* __restrict__ adj,
           const float* __restrict__ pi_eff, float* __restrict__ out) {
    __shared__ float ealpha[Z];
    __shared__ float red[8];
    const int b = blockIdx.x;
    const int j = threadIdx.x;
    const int wid = j >> 6, lane = j & 63;
    const float adjj = adj[j];
    const int id0 = ids[b];
    float alpha = emit[(size_t)id0 * Z + j] + pi_eff[j];

    for (int t = 1; t < SEQ; ++t) {
        const int id = ids[t * NB + b];
        const float obs = emit[(size_t)id * Z + j];   // issued early, hides under dot
        // block max of alpha
        float m = alpha;
        #pragma unroll
        for (int off = 32; off > 0; off >>= 1) m = fmaxf(m, __shfl_xor(m, off));
        if (lane == 0) red[wid] = m;
        __syncthreads();
        float m_a = red[0];
        #pragma unroll
        for (int k = 1; k < 8; ++k) m_a = fmaxf(m_a, red[k]);
        ealpha[j] = __expf(alpha - m_a);
        __syncthreads();
        // s[j] = sum_i ealpha[i] * E_Tt[i*Z + j]   (coalesced over j)
        float s0 = 0.f, s1 = 0.f, s2 = 0.f, s3 = 0.f;
        const float* p = E_Tt + j;
        #pragma unroll 4
        for (int i4 = 0; i4 < Z / 4; ++i4) {
            const float4 ea = *reinterpret_cast<const float4*>(ealpha + (i4 << 2));
            const float* q = p + (size_t)(i4 << 2) * Z;
            s0 = fmaf(ea.x, q[0],     s0);
            s1 = fmaf(ea.y, q[Z],     s1);
            s2 = fmaf(ea.z, q[2 * Z], s2);
            s3 = fmaf(ea.w, q[3 * Z], s3);
        }
        const float s = (s0 + s1) + (s2 + s3);
        alpha = obs + adjj + m_a + __logf(s);
        __syncthreads();   // protect red[] / ealpha for next iteration
    }

    // final logsumexp over states
    float m = alpha;
    #pragma unroll
    for (int off = 32; off > 0; off >>= 1) m = fmaxf(m, __shfl_xor(m, off));
    if (lane == 0) red[wid] = m;
    __syncthreads();
    float m_a = red[0];
    #pragma unroll
    for (int k = 1; k < 8; ++k) m_a = fmaxf(m_a, red[k]);
    float e = __expf(alpha - m_a);
    #pragma unroll
    for (int off = 32; off > 0; off >>= 1) e += __shfl_xor(e, off);
    __syncthreads();
    if (lane == 0) red[wid] = e;
    __syncthreads();
    if (j == 0) {
        float tot = 0.f;
        #pragma unroll
        for (int k = 0; k < 8; ++k) tot += red[k];
        out[b] = -(m_a + __logf(tot));
    }
}

extern "C" void kernel_launch(void* const* d_in, const int* in_sizes, int n_in,
                              void* d_out, int out_size, void* d_ws, size_t ws_size,
                              hipStream_t stream) {
    const int*   ids  = (const int*)d_in[0];    // [256,64]
    const float* T    = (const float*)d_in[1];  // [512,512]
    const float* pi   = (const float*)d_in[2];  // [512]
    const float* emit = (const float*)d_in[3];  // [10000,512]
    float* out = (float*)d_out;                 // [64]

    float* ws = (float*)d_ws;
    float*  E_Tt     = ws;                 // 262144 floats (1 MB)
    float*  colLSE   = ws + 262144;        // 512
    float*  adj      = ws + 262656;        // 512
    float*  pi_eff   = ws + 263168;        // 512
    float*  emit_lse = ws + 263680;        // 512
    float2* em_part  = (float2*)(ws + 264192); // 32*512 float2 = 32768 floats

    hipLaunchKernelGGL(k_t_collse, dim3(8),   dim3(256), 0, stream, T, colLSE);
    hipLaunchKernelGGL(k_emit_part, dim3(256), dim3(256), 0, stream, emit, em_part);
    hipLaunchKernelGGL(k_finalize, dim3(1),   dim3(512), 0, stream, em_part, pi, emit_lse, pi_eff);
    hipLaunchKernelGGL(k_build_ET, dim3(512), dim3(256), 0, stream, T, colLSE, emit_lse, E_Tt, adj);
    hipLaunchKernelGGL(k_hmm_scan, dim3(64),  dim3(512), 0, stream, ids, emit, E_Tt, adj, pi_eff, out);
}

// Round 2
// 1233.955 us; speedup vs baseline: 1.7563x; 1.7563x over previous
//
#include <hip/hip_runtime.h>
#include <math.h>

#define Z 512
#define XV 10000
#define SEQ 256
#define NB 64

typedef _Float16 h2t __attribute__((ext_vector_type(2)));

__device__ __forceinline__ float dot2f(unsigned a, unsigned b, float c) {
#if __has_builtin(__builtin_amdgcn_fdot2)
    return __builtin_amdgcn_fdot2(__builtin_bit_cast(h2t, a), __builtin_bit_cast(h2t, b), c, false);
#else
    h2t av = __builtin_bit_cast(h2t, a), bv = __builtin_bit_cast(h2t, b);
    return fmaf((float)av[0], (float)bv[0], fmaf((float)av[1], (float)bv[1], c));
#endif
}

__device__ __forceinline__ unsigned pack_h2(float a, float b) {
    h2t v; v[0] = (_Float16)a; v[1] = (_Float16)b;
    return __builtin_bit_cast(unsigned, v);
}

__device__ __forceinline__ void online_combine(float& m, float& s, float pm, float ps) {
    if (pm > m) { s = s * __expf(m - pm) + ps; m = pm; }
    else        { s = s + ps * __expf(pm - m); }
}

// K1: column-wise LSE of T over axis 0 (rows). grid=8 (64 cols each), block=256.
__global__ void k_t_collse(const float* __restrict__ T, float* __restrict__ colLSE) {
    __shared__ float ms[256], ss[256];
    const int tid = threadIdx.x;
    const int c0 = blockIdx.x * 64;
    const int cl = tid & 63;
    const int r0 = tid >> 6;           // 0..3
    const int c  = c0 + cl;
    float m = -INFINITY, s = 0.f;
    for (int r = r0; r < Z; r += 4)
        online_combine(m, s, T[(size_t)r * Z + c], 1.f);
    ms[tid] = m; ss[tid] = s;
    __syncthreads();
    if (tid < 128) {
        m = ms[tid]; s = ss[tid];
        online_combine(m, s, ms[tid + 128], ss[tid + 128]);
        ms[tid] = m; ss[tid] = s;
    }
    __syncthreads();
    if (tid < 64) {
        m = ms[tid]; s = ss[tid];
        online_combine(m, s, ms[tid + 64], ss[tid + 64]);
        colLSE[c0 + tid] = m + __logf(s);
    }
}

// K2: emit column-wise LSE partials. grid=256 (8 colgroups x 32 rowgroups), block=256.
__global__ void k_emit_part(const float* __restrict__ emit, float2* __restrict__ part) {
    __shared__ float ms[256], ss[256];
    const int tid = threadIdx.x;
    const int g  = blockIdx.x & 7;
    const int rg = blockIdx.x >> 3;
    const int cl = tid & 63;
    const int r0 = tid >> 6;
    const int c  = g * 64 + cl;
    const int rstart = rg * 313;
    const int rend   = (rstart + 313 < XV) ? rstart + 313 : XV;
    float m = -INFINITY, s = 0.f;
    for (int r = rstart + r0; r < rend; r += 4)
        online_combine(m, s, emit[(size_t)r * Z + c], 1.f);
    ms[tid] = m; ss[tid] = s;
    __syncthreads();
    if (tid < 128) {
        m = ms[tid]; s = ss[tid];
        online_combine(m, s, ms[tid + 128], ss[tid + 128]);
        ms[tid] = m; ss[tid] = s;
    }
    __syncthreads();
    if (tid < 64) {
        m = ms[tid]; s = ss[tid];
        online_combine(m, s, ms[tid + 64], ss[tid + 64]);
        part[(size_t)rg * Z + g * 64 + tid] = make_float2(m, s);
    }
}

// K3: finalize emit_lse per state; compute pi_eff = pi_log - emit_lse. grid=1, block=512.
__global__ void k_finalize(const float2* __restrict__ part, const float* __restrict__ pi,
                           float* __restrict__ emit_lse, float* __restrict__ pi_eff) {
    __shared__ float sm[512];
    const int z = threadIdx.x;
    float m = -INFINITY, s = 0.f;
    for (int rg = 0; rg < 32; ++rg) {
        float2 p = part[(size_t)rg * Z + z];
        online_combine(m, s, p.x, p.y);
    }
    const float el = m + __logf(s);
    emit_lse[z] = el;
    const float v = pi[z];
    sm[z] = v; __syncthreads();
    for (int off = 256; off > 0; off >>= 1) {
        if (z < off) sm[z] = fmaxf(sm[z], sm[z + off]);
        __syncthreads();
    }
    const float mx = sm[0];
    __syncthreads();
    sm[z] = __expf(v - mx); __syncthreads();
    for (int off = 256; off > 0; off >>= 1) {
        if (z < off) sm[z] += sm[z + off];
        __syncthreads();
    }
    const float lse_pi = mx + __logf(sm[0]);
    pi_eff[z] = (v - lse_pi) - el;
}

// K4: build fp16-packed M[k][j] = half2(E[2k][j], E[2k+1][j]) where
// E[i][j] = exp(T_log[j][i] - mT[j]); adj[j] = mT[j] - emit_lse[j].
// grid=512 (one block per row j), block=256.
__global__ void k_build_ET(const float* __restrict__ T, const float* __restrict__ colLSE,
                           const float* __restrict__ emit_lse,
                           _Float16* __restrict__ H, float* __restrict__ adj) {
    __shared__ float sm[256];
    const int j = blockIdx.x, t = threadIdx.x;
    const float v0 = T[(size_t)j * Z + t]       - colLSE[t];
    const float v1 = T[(size_t)j * Z + t + 256] - colLSE[t + 256];
    float m = fmaxf(v0, v1);
    sm[t] = m; __syncthreads();
    for (int off = 128; off > 0; off >>= 1) {
        if (t < off) sm[t] = fmaxf(sm[t], sm[t + off]);
        __syncthreads();
    }
    const float mT = sm[0];
    // half index: k*1024 + 2*j + (i&1), k = i>>1
    H[(size_t)(t >> 1) * 1024 + 2 * j + (t & 1)]         = (_Float16)__expf(v0 - mT);
    H[(size_t)((t + 256) >> 1) * 1024 + 2 * j + (t & 1)] = (_Float16)__expf(v1 - mT);
    if (t == 0) adj[j] = mT - emit_lse[j];
}

// K5: sequential scan. One block (1024 threads) per batch element.
// Thread (g,h): g=tid&127 owns states j=4g..4g+3; h=tid>>7 owns i-pairs k in [32h,32h+32).
__global__ void __launch_bounds__(1024, 4)
k_hmm_scan(const int* __restrict__ ids, const float* __restrict__ emit,
           const unsigned* __restrict__ Mbuf, const float* __restrict__ adj,
           const float* __restrict__ pi_eff, float* __restrict__ out) {
    __shared__ float sred[8][Z];
    __shared__ unsigned ea2u[Z / 2];
    __shared__ float redm[16];
    const int b = blockIdx.x;
    const int tid = threadIdx.x;
    const int lane = tid & 63, wid = tid >> 6;
    const int g = tid & 127;
    const int h = tid >> 7;
    const uint4* mp = (const uint4*)Mbuf;

    float alpha = 0.f, adjj = 0.f, m_a;
    if (tid < Z) {
        adjj = adj[tid];
        alpha = emit[(size_t)ids[b] * Z + tid] + pi_eff[tid];
    }
    {   // initial block max + ealpha pack
        float mv = (tid < Z) ? alpha : -INFINITY;
        #pragma unroll
        for (int off = 32; off > 0; off >>= 1) mv = fmaxf(mv, __shfl_xor(mv, off));
        if (lane == 0) redm[wid] = mv;
        __syncthreads();
        float nm = redm[0];
        #pragma unroll
        for (int k = 1; k < 16; ++k) nm = fmaxf(nm, redm[k]);
        m_a = nm;
        if (tid < Z) {
            float e = __expf(alpha - m_a);
            float eo = __shfl_xor(e, 1);
            if (!(tid & 1)) ea2u[tid >> 1] = pack_h2(e, eo);
        }
        __syncthreads();
    }

    for (int t = 1; t < SEQ; ++t) {
        const int id = ids[t * NB + b];
        float obs = 0.f;
        if (tid < Z) obs = emit[(size_t)id * Z + tid];   // hides under the dot

        float s0 = 0.f, s1 = 0.f, s2 = 0.f, s3 = 0.f;
        #pragma unroll 8
        for (int kk = 0; kk < 32; kk += 2) {
            const int k = (h << 5) + kk;
            const uint2 ea = *(const uint2*)(ea2u + k);          // LDS broadcast
            const uint4 ma = mp[(size_t)k * 128 + g];
            const uint4 mb = mp[(size_t)(k + 1) * 128 + g];
            s0 = dot2f(ea.x, ma.x, s0); s1 = dot2f(ea.x, ma.y, s1);
            s2 = dot2f(ea.x, ma.z, s2); s3 = dot2f(ea.x, ma.w, s3);
            s0 = dot2f(ea.y, mb.x, s0); s1 = dot2f(ea.y, mb.y, s1);
            s2 = dot2f(ea.y, mb.z, s2); s3 = dot2f(ea.y, mb.w, s3);
        }
        *(float4*)(&sred[h][g << 2]) = make_float4(s0, s1, s2, s3);
        __syncthreads();                                   // S1

        float mv = -INFINITY;
        if (tid < Z) {
            float s = 0.f;
            #pragma unroll
            for (int hh = 0; hh < 8; ++hh) s += sred[hh][tid];
            alpha = obs + adjj + m_a + __logf(s);
            mv = alpha;
        }
        #pragma unroll
        for (int off = 32; off > 0; off >>= 1) mv = fmaxf(mv, __shfl_xor(mv, off));
        if (lane == 0) redm[wid] = mv;
        __syncthreads();                                   // S2
        float nm = redm[0];
        #pragma unroll
        for (int k = 1; k < 16; ++k) nm = fmaxf(nm, redm[k]);
        m_a = nm;
        if (tid < Z) {
            float e = __expf(alpha - m_a);
            float eo = __shfl_xor(e, 1);
            if (!(tid & 1)) ea2u[tid >> 1] = pack_h2(e, eo);
        }
        __syncthreads();                                   // S3
    }

    float ev = (tid < Z) ? __expf(alpha - m_a) : 0.f;
    #pragma unroll
    for (int off = 32; off > 0; off >>= 1) ev += __shfl_xor(ev, off);
    if (lane == 0) redm[wid] = ev;
    __syncthreads();
    if (tid == 0) {
        float tot = 0.f;
        #pragma unroll
        for (int k = 0; k < 16; ++k) tot += redm[k];
        out[b] = -(m_a + __logf(tot));
    }
}

extern "C" void kernel_launch(void* const* d_in, const int* in_sizes, int n_in,
                              void* d_out, int out_size, void* d_ws, size_t ws_size,
                              hipStream_t stream) {
    const int*   ids  = (const int*)d_in[0];    // [256,64]
    const float* T    = (const float*)d_in[1];  // [512,512]
    const float* pi   = (const float*)d_in[2];  // [512]
    const float* emit = (const float*)d_in[3];  // [10000,512]
    float* out = (float*)d_out;                 // [64]

    float* wsf = (float*)d_ws;
    unsigned* Mbuf   = (unsigned*)wsf;          // 131072 dwords = 512 KB (fp16-packed E_T)
    float*  colLSE   = wsf + 131072;
    float*  adj      = wsf + 131584;
    float*  pi_eff   = wsf + 132096;
    float*  emit_lse = wsf + 132608;
    float2* em_part  = (float2*)(wsf + 133120); // 32*512 float2

    hipLaunchKernelGGL(k_t_collse,  dim3(8),   dim3(256), 0, stream, T, colLSE);
    hipLaunchKernelGGL(k_emit_part, dim3(256), dim3(256), 0, stream, emit, em_part);
    hipLaunchKernelGGL(k_finalize,  dim3(1),   dim3(512), 0, stream, em_part, pi, emit_lse, pi_eff);
    hipLaunchKernelGGL(k_build_ET,  dim3(512), dim3(256), 0, stream, T, colLSE, emit_lse,
                       (_Float16*)Mbuf, adj);
    hipLaunchKernelGGL(k_hmm_scan,  dim3(64),  dim3(1024), 0, stream, ids, emit, Mbuf, adj,
                       pi_eff, out);
}